// Round 1
// baseline (459.845 us; speedup 1.0000x reference)
//
#include <hip/hip_runtime.h>

typedef unsigned short u16;
typedef __attribute__((ext_vector_type(8))) short bh8;   // 8 bf16 in 4 VGPRs
typedef __attribute__((ext_vector_type(4))) float f4;

__device__ inline u16 f2bf(float f) {
  union { float f; unsigned u; } v; v.f = f;
  unsigned r = v.u + 0x7FFFu + ((v.u >> 16) & 1u);   // RNE
  return (u16)(r >> 16);
}

// ---------------- conversion: x (fp32) -> bf16 ----------------
__global__ __launch_bounds__(256) void convx_kernel(const float* __restrict__ x,
                                                    u16* __restrict__ xb, int n8) {
  int i = blockIdx.x * 256 + threadIdx.x;
  if (i >= n8) return;
  const float4* xf = (const float4*)x;
  float4 a = xf[2 * i], b = xf[2 * i + 1];
  alignas(16) u16 o[8] = { f2bf(a.x), f2bf(a.y), f2bf(a.z), f2bf(a.w),
                           f2bf(b.x), f2bf(b.y), f2bf(b.z), f2bf(b.w) };
  *(int4*)(xb + (size_t)i * 8) = *(const int4*)o;
}

// ------------- transpose + convert: W[K][N] fp32 -> Wt[N][K] bf16 -------------
__global__ __launch_bounds__(256) void tconv_kernel(const float* __restrict__ W,
                                                    u16* __restrict__ Wt,
                                                    int K, int N) {
  __shared__ float tile[32][33];
  int nb = blockIdx.x * 32, kb = blockIdx.y * 32;
  int tx = threadIdx.x, ty = threadIdx.y;
  for (int i = ty; i < 32; i += 8)
    tile[i][tx] = W[(size_t)(kb + i) * N + nb + tx];
  __syncthreads();
  for (int i = ty; i < 32; i += 8)
    Wt[(size_t)(nb + i) * K + kb + tx] = f2bf(tile[tx][i]);
}

// ---------------- async global->LDS 16B ----------------
__device__ inline void gload16(const u16* g, u16* l) {
  __builtin_amdgcn_global_load_lds(
      (const __attribute__((address_space(1))) unsigned int*)g,
      (__attribute__((address_space(3))) unsigned int*)l, 16, 0, 0);
}

// ---------------- GEMM: C[M][N] = A[M][K] * Bt[N][K]^T  (m97 structure) ----------------
template <typename OutT>
__global__ __launch_bounds__(256) void gemm_bt(const u16* __restrict__ A,
                                               const u16* __restrict__ Bt,
                                               OutT* __restrict__ C,
                                               int M, int N, int K) {
  __shared__ u16 As[128 * 32];
  __shared__ u16 Bs[128 * 32];
  const int t = threadIdx.x;
  const int lane = t & 63, w = t >> 6;
  const int wr = w >> 1, wc = w & 1;
  const int fr = lane & 15, fq = lane >> 4;
  const int rowBase = blockIdx.y * 128, colBase = blockIdx.x * 128;
  f4 acc[4][4] = {};
  const u16* Ag = A + (size_t)rowBase * K;
  const u16* Bg = Bt + (size_t)colBase * K;
  for (int kt = 0; kt < K; kt += 32) {
    __syncthreads();
#pragma unroll
    for (int i = 0; i < 2; i++) {
      int c = t + i * 256;                     // 16B chunk id: row=c>>2, kofs=(c&3)*8
      gload16(Ag + (size_t)(c >> 2) * K + kt + (c & 3) * 8, As + c * 8);
    }
#pragma unroll
    for (int i = 0; i < 2; i++) {
      int c = t + i * 256;
      gload16(Bg + (size_t)(c >> 2) * K + kt + (c & 3) * 8, Bs + c * 8);
    }
    __syncthreads();
    bh8 a[4], b[4];
#pragma unroll
    for (int m = 0; m < 4; m++)
      a[m] = *(const bh8*)(As + (wr * 64 + m * 16 + fr) * 32 + fq * 8);
#pragma unroll
    for (int n = 0; n < 4; n++)
      b[n] = *(const bh8*)(Bs + (wc * 64 + n * 16 + fr) * 32 + fq * 8);
#pragma unroll
    for (int m = 0; m < 4; m++)
#pragma unroll
      for (int n = 0; n < 4; n++)
        acc[m][n] = __builtin_amdgcn_mfma_f32_16x16x32_bf16(a[m], b[n], acc[m][n], 0, 0, 0);
  }
#pragma unroll
  for (int m = 0; m < 4; m++)
#pragma unroll
    for (int n = 0; n < 4; n++)
#pragma unroll
      for (int r = 0; r < 4; r++) {
        int row = rowBase + wr * 64 + m * 16 + fq * 4 + r;   // C: row=(l>>4)*4+reg
        int col = colBase + wc * 64 + n * 16 + fr;           //    col=l&15
        float v = acc[m][n][r];
        if constexpr (sizeof(OutT) == 2)
          ((u16*)C)[(size_t)row * N + col] = f2bf(v);
        else
          ((float*)C)[(size_t)row * N + col] = v;
      }
}

// ---------------- fused flash attention (GQA, no mask) ----------------
// QKV: [4096][3072] bf16, Q cols 0..2047 (h*64), K cols 2048..2559, V cols 2560..3071
// AO:  [4096][2048] bf16
__global__ __launch_bounds__(256) void attn_kernel(const u16* __restrict__ QKV,
                                                   u16* __restrict__ AO) {
  constexpr int LD = 72;   // pad: 144B row stride -> 2-way (free) aliasing on b128 reads
  __shared__ u16 Ks[64][LD];
  __shared__ u16 Vt[64][LD];          // Vt[hd][key]
  __shared__ u16 Plds[4][16][LD];     // per-wave P re-layout buffer
  const int t = threadIdx.x, lane = t & 63, w = t >> 6;
  const int fr = lane & 15, fq = lane >> 4;
  const int blk = blockIdx.x;
  const int qb = blk & 31;            // q-tile (N/64 = 32)
  const int h = (blk >> 5) & 31;      // head
  const int b = blk >> 10;            // batch
  const int kvh = h >> 2;             // GQA: 4 q-heads per kv-head
  const size_t rowb = (size_t)b * 2048;
  const u16* Qb = QKV + rowb * 3072 + h * 64;
  const u16* Kb = QKV + rowb * 3072 + 2048 + kvh * 64;
  const u16* Vb = QKV + rowb * 3072 + 2560 + kvh * 64;

  // Q fragments: wave w owns q rows qb*64 + w*16 + [0,16)
  bh8 qf0 = *(const bh8*)(Qb + (size_t)(qb * 64 + w * 16 + fr) * 3072 + fq * 8);
  bh8 qf1 = *(const bh8*)(Qb + (size_t)(qb * 64 + w * 16 + fr) * 3072 + 32 + fq * 8);

  float mrow[4] = {-1e30f, -1e30f, -1e30f, -1e30f};
  float lrow[4] = {0.f, 0.f, 0.f, 0.f};
  f4 oacc[4] = {};

  for (int kb = 0; kb < 32; kb++) {
    __syncthreads();                   // previous iter done with Ks/Vt
    // stage K tile [64 keys][64 hd] (coalesced 16B)
#pragma unroll
    for (int i = 0; i < 2; i++) {
      int c = t + i * 256;
      int kr = c >> 3, ko = (c & 7) * 8;
      *(int4*)&Ks[kr][ko] = *(const int4*)(Kb + (size_t)(kb * 64 + kr) * 3072 + ko);
    }
    // stage V transposed: Vt[hd][key]
#pragma unroll
    for (int i = 0; i < 2; i++) {
      int c = t + i * 256;
      int vr = c >> 3, vo = (c & 7) * 8;
      int4 vv = *(const int4*)(Vb + (size_t)(kb * 64 + vr) * 3072 + vo);
      u16* pv = (u16*)&vv;
#pragma unroll
      for (int j = 0; j < 8; j++) Vt[vo + j][vr] = pv[j];
    }
    __syncthreads();

    // S = (Q K^T) * 0.125 ; frag: row(q)=fq*4+r, col(key)=c*16+fr
    f4 sf[4];
#pragma unroll
    for (int c = 0; c < 4; c++) {
      bh8 k0 = *(const bh8*)&Ks[c * 16 + fr][fq * 8];
      bh8 k1 = *(const bh8*)&Ks[c * 16 + fr][32 + fq * 8];
      f4 s = {};
      s = __builtin_amdgcn_mfma_f32_16x16x32_bf16(qf0, k0, s, 0, 0, 0);
      s = __builtin_amdgcn_mfma_f32_16x16x32_bf16(qf1, k1, s, 0, 0, 0);
#pragma unroll
      for (int r = 0; r < 4; r++) sf[c][r] = s[r] * 0.125f;
    }
    // online softmax: row-reduce across the 16 lanes of each fq group
    float mx[4];
#pragma unroll
    for (int r = 0; r < 4; r++)
      mx[r] = fmaxf(fmaxf(sf[0][r], sf[1][r]), fmaxf(sf[2][r], sf[3][r]));
#pragma unroll
    for (int msk = 1; msk <= 8; msk <<= 1)
#pragma unroll
      for (int r = 0; r < 4; r++)
        mx[r] = fmaxf(mx[r], __shfl_xor(mx[r], msk, 64));
    float fsc[4], rs[4];
#pragma unroll
    for (int r = 0; r < 4; r++) {
      float mn = fmaxf(mrow[r], mx[r]);
      fsc[r] = __expf(mrow[r] - mn);
      mrow[r] = mn;
    }
#pragma unroll
    for (int c = 0; c < 4; c++)
#pragma unroll
      for (int r = 0; r < 4; r++)
        sf[c][r] = __expf(sf[c][r] - mrow[r]);
#pragma unroll
    for (int r = 0; r < 4; r++)
      rs[r] = sf[0][r] + sf[1][r] + sf[2][r] + sf[3][r];
#pragma unroll
    for (int msk = 1; msk <= 8; msk <<= 1)
#pragma unroll
      for (int r = 0; r < 4; r++)
        rs[r] += __shfl_xor(rs[r], msk, 64);
#pragma unroll
    for (int r = 0; r < 4; r++)
      lrow[r] = lrow[r] * fsc[r] + rs[r];
#pragma unroll
    for (int hc = 0; hc < 4; hc++)
#pragma unroll
      for (int r = 0; r < 4; r++)
        oacc[hc][r] *= fsc[r];
    // P -> per-wave LDS (re-layout to A-operand fragment order)
#pragma unroll
    for (int c = 0; c < 4; c++)
#pragma unroll
      for (int r = 0; r < 4; r++)
        Plds[w][fq * 4 + r][c * 16 + fr] = f2bf(sf[c][r]);
    // PV: O += P * V
    bh8 pa0 = *(const bh8*)&Plds[w][fr][fq * 8];
    bh8 pa1 = *(const bh8*)&Plds[w][fr][32 + fq * 8];
#pragma unroll
    for (int hc = 0; hc < 4; hc++) {
      bh8 v0 = *(const bh8*)&Vt[hc * 16 + fr][fq * 8];
      bh8 v1 = *(const bh8*)&Vt[hc * 16 + fr][32 + fq * 8];
      oacc[hc] = __builtin_amdgcn_mfma_f32_16x16x32_bf16(pa0, v0, oacc[hc], 0, 0, 0);
      oacc[hc] = __builtin_amdgcn_mfma_f32_16x16x32_bf16(pa1, v1, oacc[hc], 0, 0, 0);
    }
  }
#pragma unroll
  for (int hc = 0; hc < 4; hc++)
#pragma unroll
    for (int r = 0; r < 4; r++) {
      float v = oacc[hc][r] / lrow[r];
      AO[(rowb + qb * 64 + w * 16 + fq * 4 + r) * 2048 + h * 64 + hc * 16 + fr] = f2bf(v);
    }
}

extern "C" void kernel_launch(void* const* d_in, const int* in_sizes, int n_in,
                              void* d_out, int out_size, void* d_ws, size_t ws_size,
                              hipStream_t stream) {
  const float* x  = (const float*)d_in[0];
  const float* wq = (const float*)d_in[1];
  const float* wk = (const float*)d_in[2];
  const float* wv = (const float*)d_in[3];
  const float* wo = (const float*)d_in[4];
  float* out = (float*)d_out;
  char* ws = (char*)d_ws;
  // workspace layout (bytes); AO reuses xb region (xb dead after QKV GEMM)
  u16* xb    = (u16*)(ws);                               // [4096][2048] bf16, 16 MB
  u16* AO    = (u16*)(ws);                               // [4096][2048] bf16 (reuse)
  u16* wqkvT = (u16*)(ws + 16777216);                    // [3072][2048] bf16, 12 MB
  u16* woT   = (u16*)(ws + 16777216 + 12582912);         // [2048][2048] bf16, 8 MB
  u16* QKV   = (u16*)(ws + 37748736);                    // [4096][3072] bf16, 24 MB

  convx_kernel<<<4096, 256, 0, stream>>>(x, xb, 1048576);
  dim3 tb(32, 8);
  tconv_kernel<<<dim3(64, 64), tb, 0, stream>>>(wq, wqkvT, 2048, 2048);
  tconv_kernel<<<dim3(16, 64), tb, 0, stream>>>(wk, wqkvT + (size_t)2048 * 2048, 2048, 512);
  tconv_kernel<<<dim3(16, 64), tb, 0, stream>>>(wv, wqkvT + (size_t)2560 * 2048, 2048, 512);
  tconv_kernel<<<dim3(64, 64), tb, 0, stream>>>(wo, woT, 2048, 2048);

  gemm_bt<u16><<<dim3(24, 32), 256, 0, stream>>>(xb, wqkvT, QKV, 4096, 3072, 2048);
  attn_kernel<<<2048, 256, 0, stream>>>(QKV, AO);
  gemm_bt<float><<<dim3(16, 32), 256, 0, stream>>>(AO, woT, out, 4096, 2048, 2048);
}